// Round 10
// baseline (156.677 us; speedup 1.0000x reference)
//
#include <hip/hip_runtime.h>
#include <hip/hip_bf16.h>

#define T_  256
#define NN_ 2048

typedef short bf16x8 __attribute__((ext_vector_type(8)));
typedef float f32x4  __attribute__((ext_vector_type(4)));
typedef float f32x4v __attribute__((ext_vector_type(4)));
typedef unsigned u32x4v __attribute__((ext_vector_type(4)));

__device__ __forceinline__ unsigned short f2bf(float x) {
    union { float f; unsigned u; } v; v.f = x;
    unsigned r = v.u + 0x7fffu + ((v.u >> 16) & 1u);   // RTNE, finite inputs
    return (unsigned short)(r >> 16);
}
__device__ __forceinline__ float bflo(unsigned w) {
    union { unsigned u; float f; } v; v.u = w << 16; return v.f;
}
__device__ __forceinline__ float bfhi(unsigned w) {
    union { unsigned u; float f; } v; v.u = w & 0xffff0000u; return v.f;
}
__device__ __forceinline__ unsigned pkbf(float lo, float hi) {
    union { __hip_bfloat16 h; unsigned short s; } a, b;
    a.h = __float2bfloat16(lo);
    b.h = __float2bfloat16(hi);
    return (unsigned)a.s | ((unsigned)b.s << 16);
}

__device__ __forceinline__ void gld_lds16(const unsigned short* g, unsigned short* l) {
    __builtin_amdgcn_global_load_lds(
        (const __attribute__((address_space(1))) unsigned int*)g,
        (__attribute__((address_space(3))) unsigned int*)l, 16, 0, 0);
}

// ---------------------------------------------------------------------------
// cs[p*512+f] = packed bf16 (cos,sin) of 2*pi*frac(p * 10000^(-f/512)).
// Token t, channel n: p = (bit9(n)? t&15 : t>>4), f = n & 511.
// ---------------------------------------------------------------------------
__global__ void build_cs(unsigned* __restrict__ cs) {
    int idx = blockIdx.x * 256 + threadIdx.x;     // 8192 entries
    int p = idx >> 9, f = idx & 511;
    float inv = powf(10000.0f, -(float)f * (1.0f / 512.0f));
    float ph  = (float)p * inv;
    float ang = (ph - floorf(ph)) * 6.28318530717958647692f;
    float s, c;
    sincosf(ang, &s, &c);
    cs[idx] = pkbf(c, s);
}

// ---------------------------------------------------------------------------
// vtrans: V fp32 (16,256,256) -> Vt bf16 [b][d][s]  (2.1 MB).
// ---------------------------------------------------------------------------
__global__ void vtrans(const float* __restrict__ V, unsigned short* __restrict__ Vt) {
    __shared__ unsigned short Tl[64 * 72];
    const int tid = threadIdx.x;
    const int b  = blockIdx.x >> 4;
    const int s0 = ((blockIdx.x >> 2) & 3) << 6;
    const int d0 = (blockIdx.x & 3) << 6;
    const float* Vb = V + (size_t)b * 65536;
#pragma unroll
    for (int u = 0; u < 4; u++) {
        int lin = u * 256 + tid;
        int srow = lin >> 4, c4 = (lin & 15) << 2;
        float4 v = *(const float4*)(Vb + (size_t)(s0 + srow) * 256 + d0 + c4);
        Tl[(c4 + 0) * 72 + srow] = f2bf(v.x);
        Tl[(c4 + 1) * 72 + srow] = f2bf(v.y);
        Tl[(c4 + 2) * 72 + srow] = f2bf(v.z);
        Tl[(c4 + 3) * 72 + srow] = f2bf(v.w);
    }
    __syncthreads();
    unsigned short* Vtb = Vt + (size_t)b * 65536;
#pragma unroll
    for (int u = 0; u < 2; u++) {
        int lin = u * 256 + tid;
        int drow = lin >> 3, sc8 = (lin & 7) << 3;
        *(uint4*)(Vtb + (size_t)(d0 + drow) * 256 + s0 + sc8) =
            *(const uint4*)(&Tl[drow * 72 + sc8]);
    }
}

// ---------------------------------------------------------------------------
// rope_cast v5: forced-MLP via volatile inline-asm loads.
// 8 units/thread (unit = one float4).  Issue ALL 24 loads (Q,K,cs per unit)
// as volatile asm global_load_dwordx4 (cannot be reordered/collapsed by the
// compiler; outputs must stay live) -> true depth-24 pipeline.
// Manual in-order vmcnt: wait(12) -> units 0-3 ready; consume + 8 stores;
// wait(8) -> units 4-7 loads retired (8 outstanding = our stores); consume.
// sched_barrier(0) after each wait (rule #18).
// ---------------------------------------------------------------------------
#define RSC 0.02209708691207961f   // 1/sqrt(2048)

__device__ __forceinline__ f32x4v gld_f4(const float* p) {
    f32x4v d;
    asm volatile("global_load_dwordx4 %0, %1, off" : "=v"(d) : "v"(p));
    return d;
}
__device__ __forceinline__ u32x4v gld_u4(const unsigned* p) {
    u32x4v d;
    asm volatile("global_load_dwordx4 %0, %1, off" : "=v"(d) : "v"(p));
    return d;
}

__device__ __forceinline__ uint2 rot4v(f32x4v q, u32x4v c, float sc) {
    float qx = q[0] * sc, qy = q[1] * sc, qz = q[2] * sc, qw = q[3] * sc;
    uint2 o;
    o.x = pkbf(qx * bflo(c[0]) - qy * bfhi(c[0]),
               qy * bflo(c[1]) + qx * bfhi(c[1]));
    o.y = pkbf(qz * bflo(c[2]) - qw * bfhi(c[2]),
               qw * bflo(c[3]) + qz * bfhi(c[3]));
    return o;
}

__device__ __forceinline__ unsigned csoff(unsigned u) {
    unsigned t = (u >> 9) & 255u;
    unsigned p = ((u >> 7) & 1u) ? (t & 15u) : (t >> 4);
    return (p << 9) + ((u & 127u) << 2);
}

__global__ void rope_cast(const float* __restrict__ Q, const float* __restrict__ K,
                          const unsigned* __restrict__ cs,
                          unsigned short* __restrict__ Qr, unsigned short* __restrict__ Kr) {
    const unsigned gid = blockIdx.x * 256 + threadIdx.x;   // 1048576 threads

    unsigned u[8];
#pragma unroll
    for (int j = 0; j < 8; j++) u[j] = gid + (unsigned)j * 1048576u;

    f32x4v dq[8]; f32x4v dk[8]; u32x4v cc[8];

    // issue all 24 loads, per-unit order (Q,K,cs) so in-order retirement
    // completes whole units oldest-first
#pragma unroll
    for (int j = 0; j < 8; j++) {
        dq[j] = gld_f4(Q + (size_t)u[j] * 4);
        dk[j] = gld_f4(K + (size_t)u[j] * 4);
        cc[j] = gld_u4(cs + csoff(u[j]));
    }

    // units 0-3 ready when <=12 outstanding (oldest 12 = units 0-3)
    asm volatile("s_waitcnt vmcnt(12)" ::: "memory");
    __builtin_amdgcn_sched_barrier(0);
#pragma unroll
    for (int j = 0; j < 4; j++) {
        *(uint2*)(Qr + (size_t)u[j] * 4) = rot4v(dq[j], cc[j], RSC);
        *(uint2*)(Kr + (size_t)u[j] * 4) = rot4v(dk[j], cc[j], 1.0f);
    }

    // outstanding now: 12 loads (units 4-7, oldest) + 8 stores.
    // wait(8) retires the 12 loads; the 8 remaining are our stores.
    asm volatile("s_waitcnt vmcnt(8)" ::: "memory");
    __builtin_amdgcn_sched_barrier(0);
#pragma unroll
    for (int j = 4; j < 8; j++) {
        *(uint2*)(Qr + (size_t)u[j] * 4) = rot4v(dq[j], cc[j], RSC);
        *(uint2*)(Kr + (size_t)u[j] * 4) = rot4v(dk[j], cc[j], 1.0f);
    }
}

// ---------------------------------------------------------------------------
// gemm1b: scores = Qr . Kr^T  (pure bf16 GEMM, m97 recipe).
// 128x64 tile, BK=64, 256 threads (4 waves), 512 blocks.
// global_load_lds dwordx4 staging with pre-swizzled global source (T2/G21);
// swizzled conflict-free ds_read_b128 fragment reads.
// ---------------------------------------------------------------------------
__launch_bounds__(256)
__global__ void gemm1b(const unsigned short* __restrict__ Qr,
                       const unsigned short* __restrict__ Kr,
                       unsigned short* __restrict__ scores) {
    __shared__ __align__(16) unsigned short A[128 * 64];
    __shared__ __align__(16) unsigned short Bt[64 * 64];

    const int tid  = threadIdx.x;
    const int bh   = blockIdx.x & 63;          // bh%8 per XCD
    const int tile = blockIdx.x >> 6;          // 0..7
    const int ti = (tile >> 2) << 7;           // 0,128
    const int si = (tile & 3) << 6;            // 0..192

    const unsigned short* Qb = Qr + (size_t)bh * (T_ * NN_);
    const unsigned short* Kb = Kr + (size_t)bh * (T_ * NN_);

    const unsigned short* srcA[4]; unsigned short* dstA[4];
    const unsigned short* srcB[2]; unsigned short* dstB[2];
#pragma unroll
    for (int u = 0; u < 4; u++) {
        int lin = u * 256 + tid;
        int row = lin >> 3, cu = lin & 7;
        int scol = cu ^ (row & 7);             // inverse-swizzled source
        srcA[u] = Qb + (size_t)(ti + row) * NN_ + scol * 8;
        dstA[u] = &A[lin * 8];
    }
#pragma unroll
    for (int u = 0; u < 2; u++) {
        int lin = u * 256 + tid;
        int row = lin >> 3, cu = lin & 7;
        int scol = cu ^ (row & 7);
        srcB[u] = Kb + (size_t)(si + row) * NN_ + scol * 8;
        dstB[u] = &Bt[lin * 8];
    }

    const int wv = tid >> 6, lane = tid & 63;
    const int lr = lane & 15, lg = lane >> 4;
    const int m0 = (wv >> 1) * 64;
    const int n0 = (wv & 1) * 32;

    f32x4 acc[4][2];
#pragma unroll
    for (int i = 0; i < 4; i++)
#pragma unroll
        for (int j = 0; j < 2; j++) acc[i][j] = (f32x4){0.f, 0.f, 0.f, 0.f};

    for (int k0 = 0; k0 < NN_; k0 += 64) {
#pragma unroll
        for (int u = 0; u < 4; u++) gld_lds16(srcA[u] + k0, dstA[u]);
#pragma unroll
        for (int u = 0; u < 2; u++) gld_lds16(srcB[u] + k0, dstB[u]);
        __syncthreads();

#pragma unroll
        for (int kk = 0; kk < 64; kk += 32) {
            bf16x8 af[4], bfr[2];
#pragma unroll
            for (int mi = 0; mi < 4; mi++) {
                int row = m0 + mi * 16 + lr;
                int c   = (kk >> 3) + lg;
                af[mi] = *(const bf16x8*)(&A[row * 64 + ((c ^ (row & 7)) << 3)]);
            }
#pragma unroll
            for (int ni = 0; ni < 2; ni++) {
                int row = n0 + ni * 16 + lr;
                int c   = (kk >> 3) + lg;
                bfr[ni] = *(const bf16x8*)(&Bt[row * 64 + ((c ^ (row & 7)) << 3)]);
            }
#pragma unroll
            for (int mi = 0; mi < 4; mi++)
#pragma unroll
                for (int ni = 0; ni < 2; ni++)
                    acc[mi][ni] = __builtin_amdgcn_mfma_f32_16x16x32_bf16(
                        af[mi], bfr[ni], acc[mi][ni], 0, 0, 0);
        }
        __syncthreads();
    }

    unsigned short* sb = scores + (size_t)bh * (T_ * T_);
#pragma unroll
    for (int mi = 0; mi < 4; mi++) {
        int tr = ti + m0 + mi * 16 + lg * 4;
#pragma unroll
        for (int ni = 0; ni < 2; ni++) {
            int sc = si + n0 + ni * 16 + lr;
#pragma unroll
            for (int r = 0; r < 4; r++)
                sb[(size_t)(tr + r) * 256 + sc] = f2bf(acc[mi][ni][r]);
        }
    }
}

// ---------------------------------------------------------------------------
// gemm2b: out = scores @ V via Vt bf16 [d][s].  Same glds skeleton, K=256.
// ---------------------------------------------------------------------------
__launch_bounds__(256)
__global__ void gemm2b(const unsigned short* __restrict__ scores,
                       const unsigned short* __restrict__ Vt, float* __restrict__ out) {
    __shared__ __align__(16) unsigned short A[128 * 64];
    __shared__ __align__(16) unsigned short Bt[64 * 64];

    const int tid  = threadIdx.x;
    const int bh   = blockIdx.x & 63;
    const int b    = bh >> 2;
    const int tile = blockIdx.x >> 6;          // 0..7
    const int ti = (tile >> 2) << 7;           // 0,128   (t rows)
    const int d0 = (tile & 3) << 6;            // 0..192  (d cols)

    const unsigned short* Sb  = scores + (size_t)bh * 65536;
    const unsigned short* Vtb = Vt + (size_t)b * 65536;

    const unsigned short* srcA[4]; unsigned short* dstA[4];
    const unsigned short* srcB[2]; unsigned short* dstB[2];
#pragma unroll
    for (int u = 0; u < 4; u++) {
        int lin = u * 256 + tid;
        int row = lin >> 3, cu = lin & 7;
        int scol = cu ^ (row & 7);
        srcA[u] = Sb + (size_t)(ti + row) * 256 + scol * 8;
        dstA[u] = &A[lin * 8];
    }
#pragma unroll
    for (int u = 0; u < 2; u++) {
        int lin = u * 256 + tid;
        int row = lin >> 3, cu = lin & 7;
        int scol = cu ^ (row & 7);
        srcB[u] = Vtb + (size_t)(d0 + row) * 256 + scol * 8;
        dstB[u] = &Bt[lin * 8];
    }

    const int wv = tid >> 6, lane = tid & 63;
    const int lr = lane & 15, lg = lane >> 4;
    const int m0 = (wv >> 1) * 64;
    const int n0 = (wv & 1) * 32;

    f32x4 acc[4][2];
#pragma unroll
    for (int i = 0; i < 4; i++)
#pragma unroll
        for (int j = 0; j < 2; j++) acc[i][j] = (f32x4){0.f, 0.f, 0.f, 0.f};

    for (int k0 = 0; k0 < 256; k0 += 64) {
#pragma unroll
        for (int u = 0; u < 4; u++) gld_lds16(srcA[u] + k0, dstA[u]);
#pragma unroll
        for (int u = 0; u < 2; u++) gld_lds16(srcB[u] + k0, dstB[u]);
        __syncthreads();

#pragma unroll
        for (int kk = 0; kk < 64; kk += 32) {
            bf16x8 af[4], bfr[2];
#pragma unroll
            for (int mi = 0; mi < 4; mi++) {
                int row = m0 + mi * 16 + lr;
                int c   = (kk >> 3) + lg;
                af[mi] = *(const bf16x8*)(&A[row * 64 + ((c ^ (row & 7)) << 3)]);
            }
#pragma unroll
            for (int ni = 0; ni < 2; ni++) {
                int row = n0 + ni * 16 + lr;
                int c   = (kk >> 3) + lg;
                bfr[ni] = *(const bf16x8*)(&Bt[row * 64 + ((c ^ (row & 7)) << 3)]);
            }
#pragma unroll
            for (int mi = 0; mi < 4; mi++)
#pragma unroll
                for (int ni = 0; ni < 2; ni++)
                    acc[mi][ni] = __builtin_amdgcn_mfma_f32_16x16x32_bf16(
                        af[mi], bfr[ni], acc[mi][ni], 0, 0, 0);
        }
        __syncthreads();
    }

    float* ob = out + (size_t)bh * 65536;
#pragma unroll
    for (int mi = 0; mi < 4; mi++) {
        int tr = ti + m0 + mi * 16 + lg * 4;
#pragma unroll
        for (int ni = 0; ni < 2; ni++) {
            int dc = d0 + n0 + ni * 16 + lr;
#pragma unroll
            for (int r = 0; r < 4; r++)
                ob[(size_t)(tr + r) * 256 + dc] = acc[mi][ni][r];
        }
    }
}

// ---------------------------------------------------------------------------
extern "C" void kernel_launch(void* const* d_in, const int* in_sizes, int n_in,
                              void* d_out, int out_size, void* d_ws, size_t ws_size,
                              hipStream_t stream) {
    const float* Q = (const float*)d_in[0];
    const float* K = (const float*)d_in[1];
    const float* V = (const float*)d_in[2];
    float* out = (float*)d_out;

    unsigned* cs = (unsigned*)d_ws;                                        // 32 KB
    unsigned short* scores = (unsigned short*)((char*)d_ws + 32768);       // 8 MB
    unsigned short* Vt = (unsigned short*)((char*)d_ws + 32768 + 8388608); // 2 MB
    unsigned short* Qr = (unsigned short*)((char*)d_ws + 16777216);        // 64 MB
    unsigned short* Kr = (unsigned short*)((char*)d_ws + 83886080);        // 64 MB

    build_cs<<<dim3(32), dim3(256), 0, stream>>>(cs);
    vtrans<<<dim3(256), dim3(256), 0, stream>>>(V, Vt);
    rope_cast<<<dim3(4096), dim3(256), 0, stream>>>(Q, K, cs, Qr, Kr);
    gemm1b<<<dim3(512), dim3(256), 0, stream>>>(Qr, Kr, scores);
    gemm2b<<<dim3(512), dim3(256), 0, stream>>>(scores, Vt, out);
}

// Round 11
// 135.528 us; speedup vs baseline: 1.1560x; 1.1560x over previous
//
#include <hip/hip_runtime.h>
#include <hip/hip_bf16.h>

#define T_  256
#define NN_ 2048

typedef short bf16x8 __attribute__((ext_vector_type(8)));
typedef float f32x4  __attribute__((ext_vector_type(4)));
typedef unsigned u32x4 __attribute__((ext_vector_type(4)));

__device__ __forceinline__ unsigned short f2bf(float x) {
    union { float f; unsigned u; } v; v.f = x;
    unsigned r = v.u + 0x7fffu + ((v.u >> 16) & 1u);   // RTNE, finite inputs
    return (unsigned short)(r >> 16);
}
__device__ __forceinline__ float bflo(unsigned w) {
    union { unsigned u; float f; } v; v.u = w << 16; return v.f;
}
__device__ __forceinline__ float bfhi(unsigned w) {
    union { unsigned u; float f; } v; v.u = w & 0xffff0000u; return v.f;
}
__device__ __forceinline__ unsigned pkbf(float lo, float hi) {
    union { __hip_bfloat16 h; unsigned short s; } a, b;
    a.h = __float2bfloat16(lo);
    b.h = __float2bfloat16(hi);
    return (unsigned)a.s | ((unsigned)b.s << 16);
}

__device__ __forceinline__ void gld_lds16(const unsigned short* g, unsigned short* l) {
    __builtin_amdgcn_global_load_lds(
        (const __attribute__((address_space(1))) unsigned int*)g,
        (__attribute__((address_space(3))) unsigned int*)l, 16, 0, 0);
}

// ---------------------------------------------------------------------------
// prep: fused  (a) vtrans V fp32 -> Vt bf16 [b][d][s]   (blocks 0..255)
//              (b) build cs table                        (blocks 256..287)
// cs[p*512+f] = packed bf16 (cos,sin) of 2*pi*frac(p * 10000^(-f/512)).
// Token t, channel n: p = (bit9(n)? t&15 : t>>4), f = n & 511.
// ---------------------------------------------------------------------------
__global__ void prep(const float* __restrict__ V, unsigned short* __restrict__ Vt,
                     unsigned* __restrict__ cs) {
    const int tid = threadIdx.x;
    if (blockIdx.x >= 256) {
        int idx = (blockIdx.x - 256) * 256 + tid;     // 8192 entries
        int p = idx >> 9, f = idx & 511;
        float inv = powf(10000.0f, -(float)f * (1.0f / 512.0f));
        float ph  = (float)p * inv;
        float ang = (ph - floorf(ph)) * 6.28318530717958647692f;
        float s, c;
        sincosf(ang, &s, &c);
        cs[idx] = pkbf(c, s);
        return;
    }
    __shared__ unsigned short Tl[64 * 72];
    const int b  = blockIdx.x >> 4;
    const int s0 = ((blockIdx.x >> 2) & 3) << 6;
    const int d0 = (blockIdx.x & 3) << 6;
    const float* Vb = V + (size_t)b * 65536;
#pragma unroll
    for (int u = 0; u < 4; u++) {
        int lin = u * 256 + tid;
        int srow = lin >> 4, c4 = (lin & 15) << 2;
        float4 v = *(const float4*)(Vb + (size_t)(s0 + srow) * 256 + d0 + c4);
        Tl[(c4 + 0) * 72 + srow] = f2bf(v.x);
        Tl[(c4 + 1) * 72 + srow] = f2bf(v.y);
        Tl[(c4 + 2) * 72 + srow] = f2bf(v.z);
        Tl[(c4 + 3) * 72 + srow] = f2bf(v.w);
    }
    __syncthreads();
    unsigned short* Vtb = Vt + (size_t)b * 65536;
#pragma unroll
    for (int u = 0; u < 2; u++) {
        int lin = u * 256 + tid;
        int drow = lin >> 3, sc8 = (lin & 7) << 3;
        *(uint4*)(Vtb + (size_t)(d0 + drow) * 256 + s0 + sc8) =
            *(const uint4*)(&Tl[drow * 72 + sc8]);
    }
}

// ---------------------------------------------------------------------------
// rope_cast v6: v1 structure (fastest of v1-v5; all MLP-forcing variants were
// null -> not latency-bound) + NON-TEMPORAL Qr/Kr stores.  Theory W: the
// write stream thrashes L3 (Q+K=268MB vs 256MB L3; steady-state FETCH=131MB
// = half the input re-fetched).  NT stores bypass L2/L3 -> L3 left to Q+K.
// ---------------------------------------------------------------------------
#define RSC 0.02209708691207961f   // 1/sqrt(2048)

__launch_bounds__(256)
__global__ void rope_cast(const float* __restrict__ Q, const float* __restrict__ K,
                          const unsigned* __restrict__ cs,
                          unsigned short* __restrict__ Qr, unsigned short* __restrict__ Kr) {
    const size_t base = (size_t)blockIdx.x * 256 + threadIdx.x;   // < 1048576
#pragma unroll
    for (int j = 0; j < 8; j++) {
        size_t o = base + (size_t)j * 1048576;
        const float* src;
        unsigned short* dst;
        float sc;
        if (j < 4) { src = Q; dst = Qr; sc = RSC; }
        else       { src = K; dst = Kr; sc = 1.0f; o -= 4194304; }
        const int t = (int)((o >> 8) & 255);
        const int w = (int)((o >> 6) & 1);
        const int f = ((int)o & 63) << 3;
        const int p = w ? (t & 15) : (t >> 4);
        const float* qp = src + o * 8;
        float4 q0 = *(const float4*)(qp);
        float4 q1 = *(const float4*)(qp + 4);
        const unsigned* cp = cs + (p << 9) + f;
        uint4 u0 = *(const uint4*)(cp);
        uint4 u1 = *(const uint4*)(cp + 4);
        q0.x *= sc; q0.y *= sc; q0.z *= sc; q0.w *= sc;
        q1.x *= sc; q1.y *= sc; q1.z *= sc; q1.w *= sc;
        u32x4 out;
        out[0] = pkbf(q0.x*bflo(u0.x) - q0.y*bfhi(u0.x),
                      q0.y*bflo(u0.y) + q0.x*bfhi(u0.y));
        out[1] = pkbf(q0.z*bflo(u0.z) - q0.w*bfhi(u0.z),
                      q0.w*bflo(u0.w) + q0.z*bfhi(u0.w));
        out[2] = pkbf(q1.x*bflo(u1.x) - q1.y*bfhi(u1.x),
                      q1.y*bflo(u1.y) + q1.x*bfhi(u1.y));
        out[3] = pkbf(q1.z*bflo(u1.z) - q1.w*bfhi(u1.z),
                      q1.w*bflo(u1.w) + q1.z*bfhi(u1.w));
        __builtin_nontemporal_store(out, (u32x4*)(dst + o * 8));
    }
}

// ---------------------------------------------------------------------------
// gemm1b: scores = Qr . Kr^T  (pure bf16 GEMM, m97 recipe).
// 128x64 tile, BK=64, 256 threads (4 waves), 512 blocks.
// global_load_lds dwordx4 staging with pre-swizzled global source (T2/G21);
// swizzled conflict-free ds_read_b128 fragment reads.
// ---------------------------------------------------------------------------
__launch_bounds__(256)
__global__ void gemm1b(const unsigned short* __restrict__ Qr,
                       const unsigned short* __restrict__ Kr,
                       unsigned short* __restrict__ scores) {
    __shared__ __align__(16) unsigned short A[128 * 64];
    __shared__ __align__(16) unsigned short Bt[64 * 64];

    const int tid  = threadIdx.x;
    const int bh   = blockIdx.x & 63;          // bh%8 per XCD
    const int tile = blockIdx.x >> 6;          // 0..7
    const int ti = (tile >> 2) << 7;           // 0,128
    const int si = (tile & 3) << 6;            // 0..192

    const unsigned short* Qb = Qr + (size_t)bh * (T_ * NN_);
    const unsigned short* Kb = Kr + (size_t)bh * (T_ * NN_);

    const unsigned short* srcA[4]; unsigned short* dstA[4];
    const unsigned short* srcB[2]; unsigned short* dstB[2];
#pragma unroll
    for (int u = 0; u < 4; u++) {
        int lin = u * 256 + tid;
        int row = lin >> 3, cu = lin & 7;
        int scol = cu ^ (row & 7);             // inverse-swizzled source
        srcA[u] = Qb + (size_t)(ti + row) * NN_ + scol * 8;
        dstA[u] = &A[lin * 8];
    }
#pragma unroll
    for (int u = 0; u < 2; u++) {
        int lin = u * 256 + tid;
        int row = lin >> 3, cu = lin & 7;
        int scol = cu ^ (row & 7);
        srcB[u] = Kb + (size_t)(si + row) * NN_ + scol * 8;
        dstB[u] = &Bt[lin * 8];
    }

    const int wv = tid >> 6, lane = tid & 63;
    const int lr = lane & 15, lg = lane >> 4;
    const int m0 = (wv >> 1) * 64;
    const int n0 = (wv & 1) * 32;

    f32x4 acc[4][2];
#pragma unroll
    for (int i = 0; i < 4; i++)
#pragma unroll
        for (int j = 0; j < 2; j++) acc[i][j] = (f32x4){0.f, 0.f, 0.f, 0.f};

    for (int k0 = 0; k0 < NN_; k0 += 64) {
#pragma unroll
        for (int u = 0; u < 4; u++) gld_lds16(srcA[u] + k0, dstA[u]);
#pragma unroll
        for (int u = 0; u < 2; u++) gld_lds16(srcB[u] + k0, dstB[u]);
        __syncthreads();

#pragma unroll
        for (int kk = 0; kk < 64; kk += 32) {
            bf16x8 af[4], bfr[2];
#pragma unroll
            for (int mi = 0; mi < 4; mi++) {
                int row = m0 + mi * 16 + lr;
                int c   = (kk >> 3) + lg;
                af[mi] = *(const bf16x8*)(&A[row * 64 + ((c ^ (row & 7)) << 3)]);
            }
#pragma unroll
            for (int ni = 0; ni < 2; ni++) {
                int row = n0 + ni * 16 + lr;
                int c   = (kk >> 3) + lg;
                bfr[ni] = *(const bf16x8*)(&Bt[row * 64 + ((c ^ (row & 7)) << 3)]);
            }
#pragma unroll
            for (int mi = 0; mi < 4; mi++)
#pragma unroll
                for (int ni = 0; ni < 2; ni++)
                    acc[mi][ni] = __builtin_amdgcn_mfma_f32_16x16x32_bf16(
                        af[mi], bfr[ni], acc[mi][ni], 0, 0, 0);
        }
        __syncthreads();
    }

    unsigned short* sb = scores + (size_t)bh * (T_ * T_);
#pragma unroll
    for (int mi = 0; mi < 4; mi++) {
        int tr = ti + m0 + mi * 16 + lg * 4;
#pragma unroll
        for (int ni = 0; ni < 2; ni++) {
            int sc = si + n0 + ni * 16 + lr;
#pragma unroll
            for (int r = 0; r < 4; r++)
                sb[(size_t)(tr + r) * 256 + sc] = f2bf(acc[mi][ni][r]);
        }
    }
}

// ---------------------------------------------------------------------------
// gemm2b: out = scores @ V via Vt bf16 [d][s].  Same glds skeleton, K=256.
// NT stores for `out` (written once, never read -> don't pollute L2/L3).
// ---------------------------------------------------------------------------
__launch_bounds__(256)
__global__ void gemm2b(const unsigned short* __restrict__ scores,
                       const unsigned short* __restrict__ Vt, float* __restrict__ out) {
    __shared__ __align__(16) unsigned short A[128 * 64];
    __shared__ __align__(16) unsigned short Bt[64 * 64];

    const int tid  = threadIdx.x;
    const int bh   = blockIdx.x & 63;
    const int b    = bh >> 2;
    const int tile = blockIdx.x >> 6;          // 0..7
    const int ti = (tile >> 2) << 7;           // 0,128   (t rows)
    const int d0 = (tile & 3) << 6;            // 0..192  (d cols)

    const unsigned short* Sb  = scores + (size_t)bh * 65536;
    const unsigned short* Vtb = Vt + (size_t)b * 65536;

    const unsigned short* srcA[4]; unsigned short* dstA[4];
    const unsigned short* srcB[2]; unsigned short* dstB[2];
#pragma unroll
    for (int u = 0; u < 4; u++) {
        int lin = u * 256 + tid;
        int row = lin >> 3, cu = lin & 7;
        int scol = cu ^ (row & 7);
        srcA[u] = Sb + (size_t)(ti + row) * 256 + scol * 8;
        dstA[u] = &A[lin * 8];
    }
#pragma unroll
    for (int u = 0; u < 2; u++) {
        int lin = u * 256 + tid;
        int row = lin >> 3, cu = lin & 7;
        int scol = cu ^ (row & 7);
        srcB[u] = Vtb + (size_t)(d0 + row) * 256 + scol * 8;
        dstB[u] = &Bt[lin * 8];
    }

    const int wv = tid >> 6, lane = tid & 63;
    const int lr = lane & 15, lg = lane >> 4;
    const int m0 = (wv >> 1) * 64;
    const int n0 = (wv & 1) * 32;

    f32x4 acc[4][2];
#pragma unroll
    for (int i = 0; i < 4; i++)
#pragma unroll
        for (int j = 0; j < 2; j++) acc[i][j] = (f32x4){0.f, 0.f, 0.f, 0.f};

    for (int k0 = 0; k0 < 256; k0 += 64) {
#pragma unroll
        for (int u = 0; u < 4; u++) gld_lds16(srcA[u] + k0, dstA[u]);
#pragma unroll
        for (int u = 0; u < 2; u++) gld_lds16(srcB[u] + k0, dstB[u]);
        __syncthreads();

#pragma unroll
        for (int kk = 0; kk < 64; kk += 32) {
            bf16x8 af[4], bfr[2];
#pragma unroll
            for (int mi = 0; mi < 4; mi++) {
                int row = m0 + mi * 16 + lr;
                int c   = (kk >> 3) + lg;
                af[mi] = *(const bf16x8*)(&A[row * 64 + ((c ^ (row & 7)) << 3)]);
            }
#pragma unroll
            for (int ni = 0; ni < 2; ni++) {
                int row = n0 + ni * 16 + lr;
                int c   = (kk >> 3) + lg;
                bfr[ni] = *(const bf16x8*)(&Bt[row * 64 + ((c ^ (row & 7)) << 3)]);
            }
#pragma unroll
            for (int mi = 0; mi < 4; mi++)
#pragma unroll
                for (int ni = 0; ni < 2; ni++)
                    acc[mi][ni] = __builtin_amdgcn_mfma_f32_16x16x32_bf16(
                        af[mi], bfr[ni], acc[mi][ni], 0, 0, 0);
        }
        __syncthreads();
    }

    float* ob = out + (size_t)bh * 65536;
#pragma unroll
    for (int mi = 0; mi < 4; mi++) {
        int tr = ti + m0 + mi * 16 + lg * 4;
#pragma unroll
        for (int ni = 0; ni < 2; ni++) {
            int dc = d0 + n0 + ni * 16 + lr;
#pragma unroll
            for (int r = 0; r < 4; r++)
                __builtin_nontemporal_store(acc[mi][ni][r],
                                            ob + (size_t)(tr + r) * 256 + dc);
        }
    }
}

// ---------------------------------------------------------------------------
extern "C" void kernel_launch(void* const* d_in, const int* in_sizes, int n_in,
                              void* d_out, int out_size, void* d_ws, size_t ws_size,
                              hipStream_t stream) {
    const float* Q = (const float*)d_in[0];
    const float* K = (const float*)d_in[1];
    const float* V = (const float*)d_in[2];
    float* out = (float*)d_out;

    unsigned* cs = (unsigned*)d_ws;                                        // 32 KB
    unsigned short* scores = (unsigned short*)((char*)d_ws + 32768);       // 8 MB
    unsigned short* Vt = (unsigned short*)((char*)d_ws + 32768 + 8388608); // 2 MB
    unsigned short* Qr = (unsigned short*)((char*)d_ws + 16777216);        // 64 MB
    unsigned short* Kr = (unsigned short*)((char*)d_ws + 83886080);        // 64 MB

    prep<<<dim3(288), dim3(256), 0, stream>>>(V, Vt, cs);
    rope_cast<<<dim3(4096), dim3(256), 0, stream>>>(Q, K, cs, Qr, Kr);
    gemm1b<<<dim3(512), dim3(256), 0, stream>>>(Qr, Kr, scores);
    gemm2b<<<dim3(512), dim3(256), 0, stream>>>(scores, Vt, out);
}